// Round 15
// baseline (58.888 us; speedup 1.0000x reference)
//
#include <hip/hip_runtime.h>

#define NPERS 64
#define NJOINT 15
#define NDEPTH 128
#define BIGF 100000.0f
#define EPSF 1e-8f
#define INFF 3.0e38f

// element e (0..3) of float4 v, compile-time e
#define F4E(v, e) ((e) == 0 ? (v).x : (e) == 1 ? (v).y : (e) == 2 ? (v).z : (v).w)

// R14 synthesis: q-outer arithmetic order (R12/R13, bit-identical sums) with
// a live set <= 64 VGPR BY CONSTRUCTION (allocator grants need when <=64:
// R2=32, R14=56; above that it spills erratically, R9-R13).
//   - 8 waves/block, each owns an 8-candidate contiguous slice: acc = 16 regs
//   - j in 4 chunks of 4: X/Y tile = 16 regs; coef transient = 12
//   - npv-gates via readfirstlane -> provably scalar -> s_cbranch actually
//     skips work (R14's predication bug fixed)
// Occupancy: 1024 blocks x 8 waves = 32 waves/CU at VGPR<=64, LDS 36KB.
__global__ __launch_bounds__(512, 8)
void pose_match_kernel(
    const float* __restrict__ poses_3d,   // (B,NP,NJ,ND,3)
    const float* __restrict__ p2d,        // (B,NP,NJ,2)
    const float* __restrict__ vis,        // (B,NP,NJ)
    const int*   __restrict__ nper,       // (B,)
    const float* __restrict__ Rm,         // (B,3,3)
    const float* __restrict__ Tm,         // (B,3)
    const float* __restrict__ fm,         // (B,2)
    const float* __restrict__ cm,         // (B,2)
    const float* __restrict__ iw_,        // (B,)
    const float* __restrict__ ih_,        // (B,)
    float* __restrict__ out)              // (B,NP,NJ,ND)
{
    const int b    = blockIdx.x >> 6;     // 64 blocks/batch: 32 pp x 2 dh
    const int rem  = blockIdx.x & 63;
    const int pp   = rem >> 1;
    const int dh   = rem & 1;
    const int p0   = pp * 2;
    const int tid  = threadIdx.x;
    const int lane = tid & 63;
    const int d    = dh * 64 + lane;      // this thread's depth bin
    // provably-scalar wave id (physically uniform; analysis needs help, R4)
    const int wvs  = __builtin_amdgcn_readfirstlane(tid >> 6);   // 0..7

    __shared__ float4 sq[NPERS][NJOINT];  // {vis, rx, ry, _}  (epilogue)
    __shared__ float4 sco[NPERS][13];     // w[15],c | wx[15],0 | wy[15],0 |pad
    __shared__ float  bvred[8][2][64];    // [slice][person][lane]
    __shared__ int    bqred[8][2][64];

    // ---- stage raw candidate data ----
    for (int i = tid; i < NPERS * NJOINT; i += 512) {
        int q = i / NJOINT, j = i % NJOINT;
        float v  = vis[(b * NPERS + q) * NJOINT + j];
        float rx = p2d[((b * NPERS + q) * NJOINT + j) * 2 + 0];
        float ry = p2d[((b * NPERS + q) * NJOINT + j) * 2 + 1];
        sq[q][j] = make_float4(v, rx, ry, 0.0f);
    }
    __syncthreads();

    // ---- fold coefficients in registers, 12 ds_write_b128, [13]-pad ----
    if (tid < NPERS) {
        const int q = tid;
        float vs = 0.0f, t2 = 0.0f;
        #pragma unroll
        for (int j = 0; j < NJOINT; ++j) {
            float4 s = sq[q][j];
            vs += s.x;
            t2 = fmaf(s.y * s.y + s.z * s.z, s.x, t2);
        }
        float inv = 1.0f / (vs + EPSF);
        float o[48];                       // compile-time indexed only
        #pragma unroll
        for (int j = 0; j < NJOINT; ++j) {
            float4 s = sq[q][j];
            o[j]      = s.x * inv;
            o[16 + j] = 2.0f * s.x * s.y * inv;
            o[32 + j] = 2.0f * s.x * s.z * inv;
        }
        o[15] = t2 * inv;      // c term lives at w-slot j=15
        o[31] = 0.0f;
        o[47] = 0.0f;
        #pragma unroll
        for (int k = 0; k < 12; ++k)
            sco[q][k] = make_float4(o[4*k], o[4*k+1], o[4*k+2], o[4*k+3]);
    }
    __syncthreads();

    // ---- camera params (wave-uniform scalars) ----
    const float R00 = Rm[b*9+0], R01 = Rm[b*9+1], R02 = Rm[b*9+2];
    const float R10 = Rm[b*9+3], R11 = Rm[b*9+4], R12 = Rm[b*9+5];
    const float R20 = Rm[b*9+6], R21 = Rm[b*9+7], R22 = Rm[b*9+8];
    const float T0 = Tm[b*3+0], T1 = Tm[b*3+1], T2 = Tm[b*3+2];
    const float fx = fm[b*2+0], fy = fm[b*2+1];
    const float cx = cm[b*2+0], cy = cm[b*2+1];
    const float iwm1 = iw_[b] - 1.0f;
    const float ihm1 = ih_[b] - 1.0f;
    const int   npv  = nper[b];

    // this wave's contiguous slice: q in [q0, q0+nv)
    const int q0  = wvs * 8;
    const int nvs = __builtin_amdgcn_readfirstlane(
                        min(max(npv - q0, 0), 8));   // scalar -> s_cbranch

    const float* pA = poses_3d +
        ((size_t)(b * NPERS + p0    ) * NJOINT * NDEPTH + d) * 3;
    const float* pB = poses_3d +
        ((size_t)(b * NPERS + p0 + 1) * NJOINT * NDEPTH + d) * 3;

    // ---- accumulators init = c term (same fp order as R12/R13: c first) ----
    float acc0[8], acc1[8];
    #pragma unroll
    for (int k = 0; k < 8; ++k) {
        float ct = sco[q0 + k][3].w;
        acc0[k] = ct;
        acc1[k] = ct;
    }

    // ---- 4 j-chunks; per chunk: project 4(3) joints, stream coef b128s ----
    // fp order per (q, person): c, then j ascending with X-then-Y — identical
    // to R12/R13 (absmax 9.5e-7 lineage).
#define PASS(J0, NJP, KW)                                                     \
    {                                                                         \
        float XA[4], YA[4], XB[4], YB[4];                                     \
        _Pragma("unroll")                                                     \
        for (int jj = 0; jj < NJP; ++jj) {                                    \
            const int off = (J0 + jj) * NDEPTH * 3;                           \
            {                                                                 \
                float a0 = pA[off + 0] - T0;                                  \
                float a1 = pA[off + 1] - T1;                                  \
                float a2 = pA[off + 2] - T2;                                  \
                float xc0 = R00 * a0 + R01 * a1 + R02 * a2;                   \
                float xc1 = R10 * a0 + R11 * a1 + R12 * a2;                   \
                float xc2 = R20 * a0 + R21 * a1 + R22 * a2;                   \
                float r   = __builtin_amdgcn_rcpf(xc2);                       \
                XA[jj] = fmaf(fx * xc0, r, cx);                               \
                YA[jj] = fmaf(fy * xc1, r, cy);                               \
            }                                                                 \
            {                                                                 \
                float a0 = pB[off + 0] - T0;                                  \
                float a1 = pB[off + 1] - T1;                                  \
                float a2 = pB[off + 2] - T2;                                  \
                float xc0 = R00 * a0 + R01 * a1 + R02 * a2;                   \
                float xc1 = R10 * a0 + R11 * a1 + R12 * a2;                   \
                float xc2 = R20 * a0 + R21 * a1 + R22 * a2;                   \
                float r   = __builtin_amdgcn_rcpf(xc2);                       \
                XB[jj] = fmaf(fx * xc0, r, cx);                               \
                YB[jj] = fmaf(fy * xc1, r, cy);                               \
            }                                                                 \
        }                                                                     \
        _Pragma("unroll")                                                     \
        for (int g = 0; g < 2; ++g) {                                         \
            if (g * 4 < nvs) {            /* scalar -> real branch */         \
                _Pragma("unroll")                                             \
                for (int e = 0; e < 4; ++e) {                                 \
                    const int kk = g * 4 + e;                                 \
                    const int q  = q0 + kk;                                   \
                    float4 w4 = sco[q][KW];                                   \
                    float4 x4 = sco[q][4 + KW];                               \
                    float4 y4 = sco[q][8 + KW];                               \
                    _Pragma("unroll")                                         \
                    for (int jj = 0; jj < NJP; ++jj) {                        \
                        float w  = F4E(w4, jj);                               \
                        float wx = F4E(x4, jj);                               \
                        float wy = F4E(y4, jj);                               \
                        float u;                                              \
                        u = fmaf(w, XA[jj], -wx);                             \
                        acc0[kk] = fmaf(XA[jj], u, acc0[kk]);                 \
                        u = fmaf(w, YA[jj], -wy);                             \
                        acc0[kk] = fmaf(YA[jj], u, acc0[kk]);                 \
                        u = fmaf(w, XB[jj], -wx);                             \
                        acc1[kk] = fmaf(XB[jj], u, acc1[kk]);                 \
                        u = fmaf(w, YB[jj], -wy);                             \
                        acc1[kk] = fmaf(YB[jj], u, acc1[kk]);                 \
                    }                                                         \
                }                                                             \
            }                                                                 \
        }                                                                     \
    }

    if (nvs > 0) {
        PASS(0,  4, 0)
        PASS(4,  4, 1)
        PASS(8,  4, 2)
        PASS(12, 3, 3)
    }
#undef PASS

    // ---- per-wave argmin (init == np.argmin over BIG-clamped array) ----
    float bv0, bv1;
    int   bq0, bq1;
    if (npv < NPERS) { bv0 = bv1 = BIGF; bq0 = bq1 = npv; }
    else             { bv0 = bv1 = INFF; bq0 = bq1 = 0;   }
    #pragma unroll
    for (int k = 0; k < 8; ++k) {
        if (k < nvs) {
            float d0 = acc0[k];
            float d1 = acc1[k];
            if (d0 < bv0) { bv0 = d0; bq0 = q0 + k; }
            if (d1 < bv1) { bv1 = d1; bq1 = q0 + k; }
        }
    }
    bvred[wvs][0][lane] = bv0;  bqred[wvs][0][lane] = bq0;
    bvred[wvs][1][lane] = bv1;  bqred[wvs][1][lane] = bq1;
    __syncthreads();

    // ---- waves 0,1 finish person 0,1: combine (value,q) + epilogue ----
#define EPILOGUE(PI, PPTR)                                                    \
    if (wvs == PI) {                                                          \
        float bestv = bvred[0][PI][lane];                                     \
        int   bestq = bqred[0][PI][lane];                                     \
        _Pragma("unroll")                                                     \
        for (int k = 1; k < 8; ++k) {                                         \
            float v  = bvred[k][PI][lane];                                    \
            int   qq = bqred[k][PI][lane];                                    \
            if (v < bestv || (v == bestv && qq < bestq)) {                    \
                bestv = v; bestq = qq;                                        \
            }                                                                 \
        }                                                                     \
        const int obase = ((b * NPERS + p0 + PI) * NJOINT) * NDEPTH + d;      \
        _Pragma("unroll")                                                     \
        for (int j = 0; j < NJOINT; ++j) {                                    \
            const int off = j * NDEPTH * 3;                                   \
            float a0 = PPTR[off + 0] - T0;                                    \
            float a1 = PPTR[off + 1] - T1;                                    \
            float a2 = PPTR[off + 2] - T2;                                    \
            float xc0 = R00 * a0 + R01 * a1 + R02 * a2;                       \
            float xc1 = R10 * a0 + R11 * a1 + R12 * a2;                       \
            float xc2 = R20 * a0 + R21 * a1 + R22 * a2;                       \
            float r   = __builtin_amdgcn_rcpf(xc2);                           \
            float xx  = fmaf(fx * xc0, r, cx);                                \
            float yy  = fmaf(fy * xc1, r, cy);                                \
            float4 v = sq[bestq][j];                                          \
            float dx = xx - v.y;                                              \
            float dy = yy - v.z;                                              \
            float md = fmaf(dx, dx, dy * dy);                                 \
            float sc = __expf(-md * (1.0f / 225.0f));                         \
            float inb = (xx >= 0.0f && yy >= 0.0f &&                          \
                         xx <= iwm1 && yy <= ihm1) ? 1.0f : 0.0f;             \
            out[obase + j * NDEPTH] = sc * inb * v.x;                         \
        }                                                                     \
    }

    EPILOGUE(0, pA)
    EPILOGUE(1, pB)
#undef EPILOGUE
}

extern "C" void kernel_launch(void* const* d_in, const int* in_sizes, int n_in,
                              void* d_out, int out_size, void* d_ws, size_t ws_size,
                              hipStream_t stream) {
    const float* poses_3d = (const float*)d_in[0];
    const float* p2d      = (const float*)d_in[1];
    const float* vis      = (const float*)d_in[2];
    const int*   nper     = (const int*)d_in[3];
    const float* Rm       = (const float*)d_in[4];
    const float* Tm       = (const float*)d_in[5];
    const float* fm       = (const float*)d_in[6];
    const float* cm       = (const float*)d_in[7];
    const float* iw       = (const float*)d_in[8];
    const float* ih       = (const float*)d_in[9];
    float* out = (float*)d_out;

    const int B = in_sizes[3];  // num_persons_ref has B elements
    dim3 grid(B * 64);          // (b, person-pair, depth-half)
    dim3 block(512);            // 8 waves = 8 contiguous q-slices
    pose_match_kernel<<<grid, block, 0, stream>>>(
        poses_3d, p2d, vis, nper, Rm, Tm, fm, cm, iw, ih, out);
}

// Round 16
// 30.427 us; speedup vs baseline: 1.9354x; 1.9354x over previous
//
#include <hip/hip_runtime.h>

#define NPERS 64
#define NJOINT 15
#define NDEPTH 128
#define BIGF 100000.0f
#define EPSF 1e-8f
#define INFF 3.0e38f

// element e (0..3) of float4 v, compile-time e
#define F4E(v, e) ((e) == 0 ? (v).x : (e) == 1 ? (v).y : (e) == 2 ? (v).z : (v).w)

// R14 (the ONLY proven spill-free structure: VGPR 56, WRITE exactly 7.68MB)
// + the one measured fix: npv-gates made provably scalar via readfirstlane
// so s_cbranch actually skips subgroups (R14's `g*4 < nv` was predicated ->
// all 64 candidates computed regardless of npv, avg npv = 32.5).
// Register rule from R9-R15: live set <= ~60 and lb(256,4) (cap 128, grants
// ~need); NEVER request 8 waves/EU (lb(512,8) capped the budget at 32-64 and
// forced memory scratch, R15).
__global__ __launch_bounds__(256, 4)
void pose_match_kernel(
    const float* __restrict__ poses_3d,   // (B,NP,NJ,ND,3)
    const float* __restrict__ p2d,        // (B,NP,NJ,2)
    const float* __restrict__ vis,        // (B,NP,NJ)
    const int*   __restrict__ nper,       // (B,)
    const float* __restrict__ Rm,         // (B,3,3)
    const float* __restrict__ Tm,         // (B,3)
    const float* __restrict__ fm,         // (B,2)
    const float* __restrict__ cm,         // (B,2)
    const float* __restrict__ iw_,        // (B,)
    const float* __restrict__ ih_,        // (B,)
    float* __restrict__ out)              // (B,NP,NJ,ND)
{
    const int b    = blockIdx.x >> 6;     // 64 blocks/batch: 32 pp x 2 dh
    const int rem  = blockIdx.x & 63;
    const int pp   = rem >> 1;
    const int dh   = rem & 1;
    const int p0   = pp * 2;
    const int tid  = threadIdx.x;
    const int lane = tid & 63;
    const int d    = dh * 64 + lane;      // this thread's depth bin
    // provably-scalar wave id (physically uniform; analysis needs help, R4)
    const int wvs  = __builtin_amdgcn_readfirstlane(tid >> 6);   // 0..3

    __shared__ float4 sq[NPERS][NJOINT];  // {vis, rx, ry, _}  (epilogue)
    __shared__ float4 sco2[NJOINT][48];   // [j][q*3/4]: (w,wx,wy) per q
    __shared__ float  sc_c[NPERS];        // c term per q
    __shared__ float  bvred[4][2][64];    // [slice][person][lane]
    __shared__ int    bqred[4][2][64];

    // ---- stage raw candidate data ----
    for (int i = tid; i < NPERS * NJOINT; i += 256) {
        int q = i / NJOINT, j = i % NJOINT;
        float v  = vis[(b * NPERS + q) * NJOINT + j];
        float rx = p2d[((b * NPERS + q) * NJOINT + j) * 2 + 0];
        float ry = p2d[((b * NPERS + q) * NJOINT + j) * 2 + 1];
        sq[q][j] = make_float4(v, rx, ry, 0.0f);
    }
    __syncthreads();

    // ---- fold coefficients, transposed store [j][q*3] ----
    if (tid < NPERS) {
        const int q = tid;
        float vs = 0.0f, t2 = 0.0f;
        #pragma unroll
        for (int j = 0; j < NJOINT; ++j) {
            float4 s = sq[q][j];
            vs += s.x;
            t2 = fmaf(s.y * s.y + s.z * s.z, s.x, t2);
        }
        float inv = 1.0f / (vs + EPSF);
        #pragma unroll
        for (int j = 0; j < NJOINT; ++j) {
            float4 s = sq[q][j];
            float* row = (float*)&sco2[j][0];
            row[q * 3 + 0] = s.x * inv;
            row[q * 3 + 1] = 2.0f * s.x * s.y * inv;
            row[q * 3 + 2] = 2.0f * s.x * s.z * inv;
        }
        sc_c[q] = t2 * inv;
    }
    __syncthreads();

    // ---- camera params (wave-uniform scalars) ----
    const float R00 = Rm[b*9+0], R01 = Rm[b*9+1], R02 = Rm[b*9+2];
    const float R10 = Rm[b*9+3], R11 = Rm[b*9+4], R12 = Rm[b*9+5];
    const float R20 = Rm[b*9+6], R21 = Rm[b*9+7], R22 = Rm[b*9+8];
    const float T0 = Tm[b*3+0], T1 = Tm[b*3+1], T2 = Tm[b*3+2];
    const float fx = fm[b*2+0], fy = fm[b*2+1];
    const float cx = cm[b*2+0], cy = cm[b*2+1];
    const float iwm1 = iw_[b] - 1.0f;
    const float ihm1 = ih_[b] - 1.0f;
    const int   npv  = nper[b];

    // this wave's contiguous slice: q in [q0, q0+nvs), nvs provably scalar
    const int q0  = wvs * 16;
    const int nvs = __builtin_amdgcn_readfirstlane(
                        min(max(npv - q0, 0), 16));

    const float* pA = poses_3d +
        ((size_t)(b * NPERS + p0    ) * NJOINT * NDEPTH + d) * 3;
    const float* pB = poses_3d +
        ((size_t)(b * NPERS + p0 + 1) * NJOINT * NDEPTH + d) * 3;

    // ---- j-outer accumulation: 32 static accumulators ----
    float acc0[16], acc1[16];
    #pragma unroll
    for (int k = 0; k < 16; ++k) { acc0[k] = 0.0f; acc1[k] = 0.0f; }

    if (nvs > 0) {                         // scalar: idle waves skip all work
        #pragma unroll 1
        for (int j = 0; j < NJOINT; ++j) {
            // project joint j for both persons (transient regs)
            const int off = j * NDEPTH * 3;
            float X0, Y0, X1, Y1;
            {
                float a0 = pA[off + 0] - T0;
                float a1 = pA[off + 1] - T1;
                float a2 = pA[off + 2] - T2;
                float xc0 = R00 * a0 + R01 * a1 + R02 * a2;
                float xc1 = R10 * a0 + R11 * a1 + R12 * a2;
                float xc2 = R20 * a0 + R21 * a1 + R22 * a2;
                float r   = __builtin_amdgcn_rcpf(xc2);
                X0 = fmaf(fx * xc0, r, cx);
                Y0 = fmaf(fy * xc1, r, cy);
            }
            {
                float a0 = pB[off + 0] - T0;
                float a1 = pB[off + 1] - T1;
                float a2 = pB[off + 2] - T2;
                float xc0 = R00 * a0 + R01 * a1 + R02 * a2;
                float xc1 = R10 * a0 + R11 * a1 + R12 * a2;
                float xc2 = R20 * a0 + R21 * a1 + R22 * a2;
                float r   = __builtin_amdgcn_rcpf(xc2);
                X1 = fmaf(fx * xc0, r, cx);
                Y1 = fmaf(fy * xc1, r, cy);
            }

            // stream coefficients: 4-candidate subgroups, 3 ds_read_b128 each;
            // g-gate is SCALAR -> s_cbranch skips work beyond npv
            #pragma unroll
            for (int g = 0; g < 4; ++g) {
                if (g * 4 < nvs) {
                    float4 r0 = sco2[j][wvs * 12 + g * 3 + 0];
                    float4 r1 = sco2[j][wvs * 12 + g * 3 + 1];
                    float4 r2 = sco2[j][wvs * 12 + g * 3 + 2];
#define ACC1(K, W, WX, WY)                                                    \
                    {                                                         \
                        float u;                                              \
                        u = fmaf((W), X0, -(WX));                             \
                        acc0[g * 4 + K] = fmaf(X0, u, acc0[g * 4 + K]);       \
                        u = fmaf((W), Y0, -(WY));                             \
                        acc0[g * 4 + K] = fmaf(Y0, u, acc0[g * 4 + K]);       \
                        u = fmaf((W), X1, -(WX));                             \
                        acc1[g * 4 + K] = fmaf(X1, u, acc1[g * 4 + K]);       \
                        u = fmaf((W), Y1, -(WY));                             \
                        acc1[g * 4 + K] = fmaf(Y1, u, acc1[g * 4 + K]);       \
                    }
                    ACC1(0, r0.x, r0.y, r0.z)
                    ACC1(1, r0.w, r1.x, r1.y)
                    ACC1(2, r1.z, r1.w, r2.x)
                    ACC1(3, r2.y, r2.z, r2.w)
#undef ACC1
                }
            }
        }
    }

    // ---- per-wave argmin (init == np.argmin over BIG-clamped array) ----
    float bv0, bv1;
    int   bq0, bq1;
    if (npv < NPERS) { bv0 = bv1 = BIGF; bq0 = bq1 = npv; }
    else             { bv0 = bv1 = INFF; bq0 = bq1 = 0;   }
    #pragma unroll
    for (int k = 0; k < 16; ++k) {
        if (k < nvs) {                     // scalar branch
            float cterm = sc_c[q0 + k];
            float d0 = acc0[k] + cterm;
            float d1 = acc1[k] + cterm;
            if (d0 < bv0) { bv0 = d0; bq0 = q0 + k; }
            if (d1 < bv1) { bv1 = d1; bq1 = q0 + k; }
        }
    }
    bvred[wvs][0][lane] = bv0;  bqred[wvs][0][lane] = bq0;
    bvred[wvs][1][lane] = bv1;  bqred[wvs][1][lane] = bq1;
    __syncthreads();

    // ---- waves 0,1 finish person 0,1: combine (value,q) + epilogue ----
#define EPILOGUE(PI, PPTR)                                                    \
    if (wvs == PI) {                                                          \
        float bestv = bvred[0][PI][lane];                                     \
        int   bestq = bqred[0][PI][lane];                                     \
        _Pragma("unroll")                                                     \
        for (int k = 1; k < 4; ++k) {                                         \
            float v  = bvred[k][PI][lane];                                    \
            int   qq = bqred[k][PI][lane];                                    \
            if (v < bestv || (v == bestv && qq < bestq)) {                    \
                bestv = v; bestq = qq;                                        \
            }                                                                 \
        }                                                                     \
        const int obase = ((b * NPERS + p0 + PI) * NJOINT) * NDEPTH + d;      \
        _Pragma("unroll")                                                     \
        for (int j = 0; j < NJOINT; ++j) {                                    \
            const int off = j * NDEPTH * 3;                                   \
            float a0 = PPTR[off + 0] - T0;                                    \
            float a1 = PPTR[off + 1] - T1;                                    \
            float a2 = PPTR[off + 2] - T2;                                    \
            float xc0 = R00 * a0 + R01 * a1 + R02 * a2;                       \
            float xc1 = R10 * a0 + R11 * a1 + R12 * a2;                       \
            float xc2 = R20 * a0 + R21 * a1 + R22 * a2;                       \
            float r   = __builtin_amdgcn_rcpf(xc2);                           \
            float xx  = fmaf(fx * xc0, r, cx);                                \
            float yy  = fmaf(fy * xc1, r, cy);                                \
            float4 v = sq[bestq][j];                                          \
            float dx = xx - v.y;                                              \
            float dy = yy - v.z;                                              \
            float md = fmaf(dx, dx, dy * dy);                                 \
            float sc = __expf(-md * (1.0f / 225.0f));                         \
            float inb = (xx >= 0.0f && yy >= 0.0f &&                          \
                         xx <= iwm1 && yy <= ihm1) ? 1.0f : 0.0f;             \
            out[obase + j * NDEPTH] = sc * inb * v.x;                         \
        }                                                                     \
    }

    EPILOGUE(0, pA)
    EPILOGUE(1, pB)
#undef EPILOGUE
}

extern "C" void kernel_launch(void* const* d_in, const int* in_sizes, int n_in,
                              void* d_out, int out_size, void* d_ws, size_t ws_size,
                              hipStream_t stream) {
    const float* poses_3d = (const float*)d_in[0];
    const float* p2d      = (const float*)d_in[1];
    const float* vis      = (const float*)d_in[2];
    const int*   nper     = (const int*)d_in[3];
    const float* Rm       = (const float*)d_in[4];
    const float* Tm       = (const float*)d_in[5];
    const float* fm       = (const float*)d_in[6];
    const float* cm       = (const float*)d_in[7];
    const float* iw       = (const float*)d_in[8];
    const float* ih       = (const float*)d_in[9];
    float* out = (float*)d_out;

    const int B = in_sizes[3];  // num_persons_ref has B elements
    dim3 grid(B * 64);          // (b, person-pair, depth-half)
    dim3 block(256);            // 4 waves = 4 contiguous q-slices
    pose_match_kernel<<<grid, block, 0, stream>>>(
        poses_3d, p2d, vis, nper, Rm, Tm, fm, cm, iw, ih, out);
}

// Round 17
// 30.074 us; speedup vs baseline: 1.9581x; 1.0117x over previous
//
#include <hip/hip_runtime.h>

#define NPERS 64
#define NJOINT 15
#define NDEPTH 128
#define BIGF 100000.0f
#define EPSF 1e-8f
#define INFF 3.0e38f

// element e (0..3) of float4 v, compile-time e
#define F4E(v, e) ((e) == 0 ? (v).x : (e) == 1 ? (v).y : (e) == 2 ? (v).z : (v).w)

// R16 + 1-deep software prefetch of poses_3d in the j-loop (R16 post-mortem:
// unroll-1 loop loaded 6 dwords at the top of each iteration and used them
// immediately -> 15 exposed HBM latencies per wave; prefetch hides each under
// the ~90-VALU FMA/LDS body of the previous j). Live set ~70 regs, within the
// proven-clean zone for lb(256,4) (R14: need 56 -> granted 56, zero scratch).
__global__ __launch_bounds__(256, 4)
void pose_match_kernel(
    const float* __restrict__ poses_3d,   // (B,NP,NJ,ND,3)
    const float* __restrict__ p2d,        // (B,NP,NJ,2)
    const float* __restrict__ vis,        // (B,NP,NJ)
    const int*   __restrict__ nper,       // (B,)
    const float* __restrict__ Rm,         // (B,3,3)
    const float* __restrict__ Tm,         // (B,3)
    const float* __restrict__ fm,         // (B,2)
    const float* __restrict__ cm,         // (B,2)
    const float* __restrict__ iw_,        // (B,)
    const float* __restrict__ ih_,        // (B,)
    float* __restrict__ out)              // (B,NP,NJ,ND)
{
    const int b    = blockIdx.x >> 6;     // 64 blocks/batch: 32 pp x 2 dh
    const int rem  = blockIdx.x & 63;
    const int pp   = rem >> 1;
    const int dh   = rem & 1;
    const int p0   = pp * 2;
    const int tid  = threadIdx.x;
    const int lane = tid & 63;
    const int d    = dh * 64 + lane;      // this thread's depth bin
    // provably-scalar wave id (physically uniform; analysis needs help, R4)
    const int wvs  = __builtin_amdgcn_readfirstlane(tid >> 6);   // 0..3

    __shared__ float4 sq[NPERS][NJOINT];  // {vis, rx, ry, _}  (epilogue)
    __shared__ float4 sco2[NJOINT][48];   // [j][q*3/4]: (w,wx,wy) per q
    __shared__ float  sc_c[NPERS];        // c term per q
    __shared__ float  bvred[4][2][64];    // [slice][person][lane]
    __shared__ int    bqred[4][2][64];

    // ---- stage raw candidate data ----
    for (int i = tid; i < NPERS * NJOINT; i += 256) {
        int q = i / NJOINT, j = i % NJOINT;
        float v  = vis[(b * NPERS + q) * NJOINT + j];
        float rx = p2d[((b * NPERS + q) * NJOINT + j) * 2 + 0];
        float ry = p2d[((b * NPERS + q) * NJOINT + j) * 2 + 1];
        sq[q][j] = make_float4(v, rx, ry, 0.0f);
    }
    __syncthreads();

    // ---- fold coefficients, transposed store [j][q*3] ----
    if (tid < NPERS) {
        const int q = tid;
        float vs = 0.0f, t2 = 0.0f;
        #pragma unroll
        for (int j = 0; j < NJOINT; ++j) {
            float4 s = sq[q][j];
            vs += s.x;
            t2 = fmaf(s.y * s.y + s.z * s.z, s.x, t2);
        }
        float inv = 1.0f / (vs + EPSF);
        #pragma unroll
        for (int j = 0; j < NJOINT; ++j) {
            float4 s = sq[q][j];
            float* row = (float*)&sco2[j][0];
            row[q * 3 + 0] = s.x * inv;
            row[q * 3 + 1] = 2.0f * s.x * s.y * inv;
            row[q * 3 + 2] = 2.0f * s.x * s.z * inv;
        }
        sc_c[q] = t2 * inv;
    }
    __syncthreads();

    // ---- camera params (wave-uniform scalars) ----
    const float R00 = Rm[b*9+0], R01 = Rm[b*9+1], R02 = Rm[b*9+2];
    const float R10 = Rm[b*9+3], R11 = Rm[b*9+4], R12 = Rm[b*9+5];
    const float R20 = Rm[b*9+6], R21 = Rm[b*9+7], R22 = Rm[b*9+8];
    const float T0 = Tm[b*3+0], T1 = Tm[b*3+1], T2 = Tm[b*3+2];
    const float fx = fm[b*2+0], fy = fm[b*2+1];
    const float cx = cm[b*2+0], cy = cm[b*2+1];
    const float iwm1 = iw_[b] - 1.0f;
    const float ihm1 = ih_[b] - 1.0f;
    const int   npv  = nper[b];

    // this wave's contiguous slice: q in [q0, q0+nvs), nvs provably scalar
    const int q0  = wvs * 16;
    const int nvs = __builtin_amdgcn_readfirstlane(
                        min(max(npv - q0, 0), 16));

    const float* pA = poses_3d +
        ((size_t)(b * NPERS + p0    ) * NJOINT * NDEPTH + d) * 3;
    const float* pB = poses_3d +
        ((size_t)(b * NPERS + p0 + 1) * NJOINT * NDEPTH + d) * 3;

    // ---- j-outer accumulation: 32 static accumulators ----
    float acc0[16], acc1[16];
    #pragma unroll
    for (int k = 0; k < 16; ++k) { acc0[k] = 0.0f; acc1[k] = 0.0f; }

    if (nvs > 0) {                         // scalar: idle waves skip all work
        // prefetch j = 0
        float cA0 = pA[0], cA1 = pA[1], cA2 = pA[2];
        float cB0 = pB[0], cB1 = pB[1], cB2 = pB[2];

        #pragma unroll 1
        for (int j = 0; j < NJOINT; ++j) {
            // ---- issue j+1's loads FIRST (clamped at the tail; L2-hot) ----
            const int offn = ((j + 1 < NJOINT) ? (j + 1) : (NJOINT - 1))
                             * NDEPTH * 3;
            float nA0 = pA[offn + 0], nA1 = pA[offn + 1], nA2 = pA[offn + 2];
            float nB0 = pB[offn + 0], nB1 = pB[offn + 1], nB2 = pB[offn + 2];

            // ---- project joint j from the prefetched registers ----
            float X0, Y0, X1, Y1;
            {
                float a0 = cA0 - T0;
                float a1 = cA1 - T1;
                float a2 = cA2 - T2;
                float xc0 = R00 * a0 + R01 * a1 + R02 * a2;
                float xc1 = R10 * a0 + R11 * a1 + R12 * a2;
                float xc2 = R20 * a0 + R21 * a1 + R22 * a2;
                float r   = __builtin_amdgcn_rcpf(xc2);
                X0 = fmaf(fx * xc0, r, cx);
                Y0 = fmaf(fy * xc1, r, cy);
            }
            {
                float a0 = cB0 - T0;
                float a1 = cB1 - T1;
                float a2 = cB2 - T2;
                float xc0 = R00 * a0 + R01 * a1 + R02 * a2;
                float xc1 = R10 * a0 + R11 * a1 + R12 * a2;
                float xc2 = R20 * a0 + R21 * a1 + R22 * a2;
                float r   = __builtin_amdgcn_rcpf(xc2);
                X1 = fmaf(fx * xc0, r, cx);
                Y1 = fmaf(fy * xc1, r, cy);
            }

            // ---- stream coefficients; scalar g-gate skips beyond npv ----
            #pragma unroll
            for (int g = 0; g < 4; ++g) {
                if (g * 4 < nvs) {
                    float4 r0 = sco2[j][wvs * 12 + g * 3 + 0];
                    float4 r1 = sco2[j][wvs * 12 + g * 3 + 1];
                    float4 r2 = sco2[j][wvs * 12 + g * 3 + 2];
#define ACC1(K, W, WX, WY)                                                    \
                    {                                                         \
                        float u;                                              \
                        u = fmaf((W), X0, -(WX));                             \
                        acc0[g * 4 + K] = fmaf(X0, u, acc0[g * 4 + K]);       \
                        u = fmaf((W), Y0, -(WY));                             \
                        acc0[g * 4 + K] = fmaf(Y0, u, acc0[g * 4 + K]);       \
                        u = fmaf((W), X1, -(WX));                             \
                        acc1[g * 4 + K] = fmaf(X1, u, acc1[g * 4 + K]);       \
                        u = fmaf((W), Y1, -(WY));                             \
                        acc1[g * 4 + K] = fmaf(Y1, u, acc1[g * 4 + K]);       \
                    }
                    ACC1(0, r0.x, r0.y, r0.z)
                    ACC1(1, r0.w, r1.x, r1.y)
                    ACC1(2, r1.z, r1.w, r2.x)
                    ACC1(3, r2.y, r2.z, r2.w)
#undef ACC1
                }
            }

            // ---- rotate prefetch registers ----
            cA0 = nA0; cA1 = nA1; cA2 = nA2;
            cB0 = nB0; cB1 = nB1; cB2 = nB2;
        }
    }

    // ---- per-wave argmin (init == np.argmin over BIG-clamped array) ----
    float bv0, bv1;
    int   bq0, bq1;
    if (npv < NPERS) { bv0 = bv1 = BIGF; bq0 = bq1 = npv; }
    else             { bv0 = bv1 = INFF; bq0 = bq1 = 0;   }
    #pragma unroll
    for (int k = 0; k < 16; ++k) {
        if (k < nvs) {                     // scalar branch
            float cterm = sc_c[q0 + k];
            float d0 = acc0[k] + cterm;
            float d1 = acc1[k] + cterm;
            if (d0 < bv0) { bv0 = d0; bq0 = q0 + k; }
            if (d1 < bv1) { bv1 = d1; bq1 = q0 + k; }
        }
    }
    bvred[wvs][0][lane] = bv0;  bqred[wvs][0][lane] = bq0;
    bvred[wvs][1][lane] = bv1;  bqred[wvs][1][lane] = bq1;
    __syncthreads();

    // ---- waves 0,1 finish person 0,1: combine (value,q) + epilogue ----
#define EPILOGUE(PI, PPTR)                                                    \
    if (wvs == PI) {                                                          \
        float bestv = bvred[0][PI][lane];                                     \
        int   bestq = bqred[0][PI][lane];                                     \
        _Pragma("unroll")                                                     \
        for (int k = 1; k < 4; ++k) {                                         \
            float v  = bvred[k][PI][lane];                                    \
            int   qq = bqred[k][PI][lane];                                    \
            if (v < bestv || (v == bestv && qq < bestq)) {                    \
                bestv = v; bestq = qq;                                        \
            }                                                                 \
        }                                                                     \
        const int obase = ((b * NPERS + p0 + PI) * NJOINT) * NDEPTH + d;      \
        _Pragma("unroll")                                                     \
        for (int j = 0; j < NJOINT; ++j) {                                    \
            const int off = j * NDEPTH * 3;                                   \
            float a0 = PPTR[off + 0] - T0;                                    \
            float a1 = PPTR[off + 1] - T1;                                    \
            float a2 = PPTR[off + 2] - T2;                                    \
            float xc0 = R00 * a0 + R01 * a1 + R02 * a2;                       \
            float xc1 = R10 * a0 + R11 * a1 + R12 * a2;                       \
            float xc2 = R20 * a0 + R21 * a1 + R22 * a2;                       \
            float r   = __builtin_amdgcn_rcpf(xc2);                           \
            float xx  = fmaf(fx * xc0, r, cx);                                \
            float yy  = fmaf(fy * xc1, r, cy);                                \
            float4 v = sq[bestq][j];                                          \
            float dx = xx - v.y;                                              \
            float dy = yy - v.z;                                              \
            float md = fmaf(dx, dx, dy * dy);                                 \
            float sc = __expf(-md * (1.0f / 225.0f));                         \
            float inb = (xx >= 0.0f && yy >= 0.0f &&                          \
                         xx <= iwm1 && yy <= ihm1) ? 1.0f : 0.0f;             \
            out[obase + j * NDEPTH] = sc * inb * v.x;                         \
        }                                                                     \
    }

    EPILOGUE(0, pA)
    EPILOGUE(1, pB)
#undef EPILOGUE
}

extern "C" void kernel_launch(void* const* d_in, const int* in_sizes, int n_in,
                              void* d_out, int out_size, void* d_ws, size_t ws_size,
                              hipStream_t stream) {
    const float* poses_3d = (const float*)d_in[0];
    const float* p2d      = (const float*)d_in[1];
    const float* vis      = (const float*)d_in[2];
    const int*   nper     = (const int*)d_in[3];
    const float* Rm       = (const float*)d_in[4];
    const float* Tm       = (const float*)d_in[5];
    const float* fm       = (const float*)d_in[6];
    const float* cm       = (const float*)d_in[7];
    const float* iw       = (const float*)d_in[8];
    const float* ih       = (const float*)d_in[9];
    float* out = (float*)d_out;

    const int B = in_sizes[3];  // num_persons_ref has B elements
    dim3 grid(B * 64);          // (b, person-pair, depth-half)
    dim3 block(256);            // 4 waves = 4 contiguous q-slices
    pose_match_kernel<<<grid, block, 0, stream>>>(
        poses_3d, p2d, vis, nper, Rm, Tm, fm, cm, iw, ih, out);
}